// Round 5
// baseline (358.630 us; speedup 1.0000x reference)
//
#include <hip/hip_runtime.h>

// SNN: 3-layer LIF, B=256, T=32, H=1024, IN=2312, OUT=10.
// Round-5 (153us G1): fp16 2-plane 3-pass, LDS-staged, 2 barriers/tile.
// Round-6 FAILED: 1 block/CU -> barrier-serialized.
// Round-7 FAILED: B per-tile from global = 1.2GB logical, FETCH 77->320MB
//   (XCD pinning didn't hold; L2/L3 thrashed to HBM). KEEP: fragment-
//   ordered weight planes (split_w_frag, absmax 0.0 verified).
// Round-8: B staged to LDS via global_load_lds(16B) from fragment planes
//   (linear dest = uniform base + lane*16, matches read layout exactly ->
//   conflict-free, no VGPR/VALU). A reg-staged + split, ds_written in
//   fragment order (conflict-free reads, no pad). BOTH operands fully
//   double-buffered -> ONE barrier per K-tile; everything a barrier drains
//   was issued one full MFMA phase earlier. BM=BN=128, 4 waves 2Mx2N
//   (64x64/wave), K=32, grid 512 = 2 blocks/CU, LDS 64KB.

#define TB 256
#define TT 32
#define TH 1024
#define TIN 2312
#define TOUT 10
#define TM (TT * TB)   // 8192 rows = (t,b)
#define NK1 74         // K-tiles of 32 for GEMM1 (2368 = 74*32)
#define NK2 32         // K-tiles for GEMM2 (1024)
#define FR 512         // f16 elems per (16 x 32) fragment

typedef _Float16 f16_t;
typedef f16_t f16x8 __attribute__((ext_vector_type(8)));
typedef float floatx4 __attribute__((ext_vector_type(4)));

__device__ __forceinline__ void split2h(float v, f16_t& a, f16_t& b) {
  a = (f16_t)v;
  b = (f16_t)(v - (float)a);
}

// async 16B global->LDS; LDS dest = wave-uniform base + lane*16.
__device__ __forceinline__ void gload16(const void* g, void* l) {
  __builtin_amdgcn_global_load_lds(
      (const __attribute__((address_space(1))) void*)g,
      (__attribute__((address_space(3))) void*)l, 16, 0, 0);
}

// W (N x K) -> 2 fp16 planes in MFMA-B-fragment order:
// P[q*plane + fid*512 + lane*8 + e] =
//   split_q(W[(n16*16 + (lane&15))*K + k32*32 + (lane>>4)*8 + e]),
// fid = n16*nk32 + k32, zero for k >= K. (Verified absmax 0.0 in round-7.)
__global__ __launch_bounds__(256) void split_w_frag(
    const float* __restrict__ W, f16_t* __restrict__ P, long plane,
    int K, int nk32) {
  const int fid = blockIdx.x * 4 + (threadIdx.x >> 6);
  const int lane = threadIdx.x & 63;
  const int n16 = fid / nk32, k32 = fid - n16 * nk32;
  const long row = n16 * 16 + (lane & 15);
  const int k0 = k32 * 32 + (lane >> 4) * 8;
  float t[8];
  if (k0 + 8 <= K) {
    float4 v0 = *(const float4*)(W + row * K + k0);
    float4 v1 = *(const float4*)(W + row * K + k0 + 4);
    t[0] = v0.x; t[1] = v0.y; t[2] = v0.z; t[3] = v0.w;
    t[4] = v1.x; t[5] = v1.y; t[6] = v1.z; t[7] = v1.w;
  } else {
    #pragma unroll
    for (int e = 0; e < 8; ++e) t[e] = 0.f;
  }
  f16x8 h0, h1;
  #pragma unroll
  for (int e = 0; e < 8; ++e) {
    f16_t a, b;
    split2h(t[e], a, b);
    h0[e] = a; h1[e] = b;
  }
  const long o = (long)fid * 512 + lane * 8;
  *(f16x8*)(P + o) = h0;
  *(f16x8*)(P + plane + o) = h1;
}

// GEMM1: 3 fp16 passes (a0b0, a1b0, a0b1); A = x fp32 split in-kernel,
// B = W1 fragment planes via global_load_lds. One barrier per K-tile.
__global__ __launch_bounds__(256, 2) void snn_gemm1(
    const float* __restrict__ Af, long sT, long sB,
    const f16_t* __restrict__ Bf, long planeB, int nk32, int K,
    const float* __restrict__ bias, float* __restrict__ C, int N) {
  __shared__ f16_t As[2 * 2 * 8 * FR];  // [buf][plane][m16][512]  32 KB
  __shared__ f16_t Bs[2 * 2 * 8 * FR];  // [buf][plane][n16][512]  32 KB

  const int tid = threadIdx.x;
  const int wave = tid >> 6, lane = tid & 63;
  const int quad = lane >> 4, l16 = lane & 15;
  const int wm = (wave & 1) * 64, wn = (wave >> 1) * 64;
  const int a16 = (wave & 1) * 4, b16 = (wave >> 1) * 4;  // frag bases
  const int mblk = blockIdx.x >> 3, nblk = blockIdx.x & 7;
  const long m0 = (long)mblk * 128, n0 = (long)nblk * 128;

  floatx4 acc[4][4];
  #pragma unroll
  for (int i = 0; i < 4; ++i)
    #pragma unroll
    for (int j = 0; j < 4; ++j) acc[i][j] = (floatx4){0.f, 0.f, 0.f, 0.f};

  // A staging: thread owns (row cr, k-half ch): 16 fp32 -> 2x2 f16x8 frags
  const int cr = tid >> 1, ch = tid & 1;
  const int am16 = cr >> 4;
  const int lnA0 = (cr & 15) | ((2 * ch) << 4);
  const int lnA1 = (cr & 15) | ((2 * ch + 1) << 4);
  float4 xv[4];
  const float* xrow = Af + ((m0 + cr) >> 8) * sT + ((m0 + cr) & 255) * sB;

  auto prefetchA = [&](int kt) {
    const int k0 = kt * 32 + ch * 16;
    #pragma unroll
    for (int u = 0; u < 4; ++u)
      xv[u] = (k0 + u * 4 < K) ? *(const float4*)(xrow + k0 + u * 4)
                               : float4{0.f, 0.f, 0.f, 0.f};
  };

  auto commitA = [&](int buf) {
    #pragma unroll
    for (int half = 0; half < 2; ++half) {
      const float* p = (const float*)&xv[half * 2];
      f16x8 p0, p1;
      #pragma unroll
      for (int e = 0; e < 8; ++e) {
        f16_t a, b;
        split2h(p[e], a, b);
        p0[e] = a; p1[e] = b;
      }
      const int ln = half ? lnA1 : lnA0;
      *(f16x8*)(&As[((buf * 2 + 0) * 8 + am16) * FR + ln * 8]) = p0;
      *(f16x8*)(&As[((buf * 2 + 1) * 8 + am16) * FR + ln * 8]) = p1;
    }
  };

  // B staging: 16 chunks of 1KB (2 planes x 8 n16-frags); wave w does 4.
  const long nbase = (n0 >> 4) * (long)nk32;
  auto gloadB = [&](int kt, int buf) {
    #pragma unroll
    for (int c = 0; c < 4; ++c) {
      const int chk = wave * 4 + c;
      const int pl = chk >> 3, n16 = chk & 7;
      const f16_t* src = Bf + pl * planeB +
                         (nbase + (long)n16 * nk32 + kt) * FR + lane * 8;
      gload16(src, &Bs[((buf * 2 + pl) * 8 + n16) * FR]);
    }
  };

  // prologue: tile0 staged; xv <- A(1)
  prefetchA(0);
  gloadB(0, 0);
  commitA(0);
  prefetchA(1);
  __syncthreads();  // drains gloadB(0) + commit(0) visible

  for (int kt = 0; kt < nk32; ++kt) {
    const int cur = kt & 1;
    // invariant: As/Bs[cur] ready; xv = A(kt+1)
    if (kt + 1 < nk32) {
      gloadB(kt + 1, cur ^ 1);  // in flight across this MFMA phase
      commitA(cur ^ 1);         // xv already arrived (prev barrier drained)
    }
    if (kt + 2 < nk32) prefetchA(kt + 2);

    f16x8 afr[2][4];
    #pragma unroll
    for (int pl = 0; pl < 2; ++pl)
      #pragma unroll
      for (int i = 0; i < 4; ++i)
        afr[pl][i] = *(const f16x8*)(
            &As[((cur * 2 + pl) * 8 + a16 + i) * FR + lane * 8]);

    #pragma unroll
    for (int pb = 0; pb < 2; ++pb) {
      f16x8 bfr[4];
      #pragma unroll
      for (int j = 0; j < 4; ++j)
        bfr[j] = *(const f16x8*)(
            &Bs[((cur * 2 + pb) * 8 + b16 + j) * FR + lane * 8]);
      const int pamax = 1 - pb;  // passes (0,0),(1,0),(0,1)
      #pragma unroll
      for (int pa = 0; pa < 2; ++pa) {
        if (pa > pamax) break;
        #pragma unroll
        for (int i = 0; i < 4; ++i)
          #pragma unroll
          for (int j = 0; j < 4; ++j)
            acc[i][j] = __builtin_amdgcn_mfma_f32_16x16x32_f16(
                afr[pa][i], bfr[j], acc[i][j], 0, 0, 0);
      }
    }
    __syncthreads();  // frag reads done; gloadB(kt+1)/commit drained+visible
  }

  // epilogue: C/D layout col=lane&15, row=quad*4+reg (verified)
  #pragma unroll
  for (int j = 0; j < 4; ++j) {
    const long col = n0 + wn + j * 16 + l16;
    const float bvv = bias[col];
    #pragma unroll
    for (int i = 0; i < 4; ++i) {
      const long row0 = m0 + wm + i * 16 + quad * 4;
      #pragma unroll
      for (int g = 0; g < 4; ++g)
        C[(row0 + g) * (long)N + col] = acc[i][j][g] + bvv;
    }
  }
}

// GEMM2: A = spikes (fp16 exact, 1 plane, reg-staged copy), B = W2
// fragment planes via global_load_lds, 2 passes. Same one-barrier loop.
__global__ __launch_bounds__(256, 2) void snn_gemm2(
    const f16_t* __restrict__ Ab, long sT, long sB,
    const f16_t* __restrict__ Bf, long planeB, int nk32,
    const float* __restrict__ bias, float* __restrict__ C, int N) {
  __shared__ f16_t As[2 * 8 * FR];      // [buf][m16][512]  16 KB
  __shared__ f16_t Bs[2 * 2 * 8 * FR];  // 32 KB

  const int tid = threadIdx.x;
  const int wave = tid >> 6, lane = tid & 63;
  const int quad = lane >> 4, l16 = lane & 15;
  const int wm = (wave & 1) * 64, wn = (wave >> 1) * 64;
  const int a16 = (wave & 1) * 4, b16 = (wave >> 1) * 4;
  const int mblk = blockIdx.x >> 3, nblk = blockIdx.x & 7;
  const long m0 = (long)mblk * 128, n0 = (long)nblk * 128;

  floatx4 acc[4][4];
  #pragma unroll
  for (int i = 0; i < 4; ++i)
    #pragma unroll
    for (int j = 0; j < 4; ++j) acc[i][j] = (floatx4){0.f, 0.f, 0.f, 0.f};

  const int cr = tid >> 1, ch = tid & 1;
  const int am16 = cr >> 4;
  const int lnA0 = (cr & 15) | ((2 * ch) << 4);
  const int lnA1 = (cr & 15) | ((2 * ch + 1) << 4);
  f16x8 av[2];
  const f16_t* arow = Ab + ((m0 + cr) >> 8) * sT + ((m0 + cr) & 255) * sB;

  auto prefetchA = [&](int kt) {
    const f16_t* p = arow + kt * 32 + ch * 16;
    av[0] = *(const f16x8*)p;
    av[1] = *(const f16x8*)(p + 8);
  };

  auto commitA = [&](int buf) {
    *(f16x8*)(&As[(buf * 8 + am16) * FR + lnA0 * 8]) = av[0];
    *(f16x8*)(&As[(buf * 8 + am16) * FR + lnA1 * 8]) = av[1];
  };

  const long nbase = (n0 >> 4) * (long)nk32;
  auto gloadB = [&](int kt, int buf) {
    #pragma unroll
    for (int c = 0; c < 4; ++c) {
      const int chk = wave * 4 + c;
      const int pl = chk >> 3, n16 = chk & 7;
      const f16_t* src = Bf + pl * planeB +
                         (nbase + (long)n16 * nk32 + kt) * FR + lane * 8;
      gload16(src, &Bs[((buf * 2 + pl) * 8 + n16) * FR]);
    }
  };

  prefetchA(0);
  gloadB(0, 0);
  commitA(0);
  prefetchA(1);
  __syncthreads();

  for (int kt = 0; kt < nk32; ++kt) {
    const int cur = kt & 1;
    if (kt + 1 < nk32) {
      gloadB(kt + 1, cur ^ 1);
      commitA(cur ^ 1);
    }
    if (kt + 2 < nk32) prefetchA(kt + 2);

    f16x8 afr[4];
    #pragma unroll
    for (int i = 0; i < 4; ++i)
      afr[i] = *(const f16x8*)(&As[(cur * 8 + a16 + i) * FR + lane * 8]);

    #pragma unroll
    for (int pb = 0; pb < 2; ++pb) {
      f16x8 bfr[4];
      #pragma unroll
      for (int j = 0; j < 4; ++j)
        bfr[j] = *(const f16x8*)(
            &Bs[((cur * 2 + pb) * 8 + b16 + j) * FR + lane * 8]);
      #pragma unroll
      for (int i = 0; i < 4; ++i)
        #pragma unroll
        for (int j = 0; j < 4; ++j)
          acc[i][j] = __builtin_amdgcn_mfma_f32_16x16x32_f16(
              afr[i], bfr[j], acc[i][j], 0, 0, 0);
    }
    __syncthreads();
  }

  #pragma unroll
  for (int j = 0; j < 4; ++j) {
    const long col = n0 + wn + j * 16 + l16;
    const float bvv = bias[col];
    #pragma unroll
    for (int i = 0; i < 4; ++i) {
      const long row0 = m0 + wm + i * 16 + quad * 4;
      #pragma unroll
      for (int g = 0; g < 4; ++g)
        C[(row0 + g) * (long)N + col] = acc[i][j][g] + bvv;
    }
  }
}

// LIF scan, fp32 in -> fp16 spikes out (spikes {0,1} exact in fp16).
__global__ __launch_bounds__(256) void lif_scan_f16(const float* __restrict__ I,
                                                    f16_t* __restrict__ S) {
  int idx = blockIdx.x * 256 + threadIdx.x;
  float v = 0.f, cur = 0.f;
  #pragma unroll
  for (int t = 0; t < TT; ++t) {
    float inp = I[(long)t * (TB * TH) + idx];
    float vd = fmaf(0.05f, cur - v, v);
    float id = cur - 0.2f * cur;
    float s = (vd > 1.0f) ? 1.0f : 0.f;
    v = (1.0f - s) * vd;
    cur = id + inp;
    S[(long)t * (TB * TH) + idx] = (f16_t)s;
  }
}

// GEMM3: one wave per row; I3[r][o] = S2[r][:] . Wout[o][:] + bout[o]
__global__ __launch_bounds__(256) void gemm3_kernel(
    const f16_t* __restrict__ S2, const float* __restrict__ Wout,
    const float* __restrict__ bout, float* __restrict__ I3) {
  int wv = (blockIdx.x * blockDim.x + threadIdx.x) >> 6;
  int lane = threadIdx.x & 63;
  if (wv >= TM) return;
  const f16_t* srow = S2 + (long)wv * TH;
  float acc[TOUT];
  #pragma unroll
  for (int o = 0; o < TOUT; ++o) acc[o] = 0.f;
  for (int k = lane; k < TH; k += 64) {
    float s = (float)srow[k];
    #pragma unroll
    for (int o = 0; o < TOUT; ++o) acc[o] = fmaf(s, Wout[o * TH + k], acc[o]);
  }
  #pragma unroll
  for (int off = 32; off > 0; off >>= 1)
    #pragma unroll
    for (int o = 0; o < TOUT; ++o) acc[o] += __shfl_down(acc[o], off, 64);
  if (lane == 0) {
    #pragma unroll
    for (int o = 0; o < TOUT; ++o) I3[(long)wv * TOUT + o] = acc[o] + bout[o];
  }
}

__global__ __launch_bounds__(256) void scan_out(const float* __restrict__ I3,
                                                float* __restrict__ out) {
  int idx = blockIdx.x * blockDim.x + threadIdx.x;
  if (idx >= TB * TOUT) return;
  float v = 0.f, cur = 0.f, cnt = 0.f;
  #pragma unroll
  for (int t = 0; t < TT; ++t) {
    float inp = I3[(long)t * (TB * TOUT) + idx];
    float vd = fmaf(0.05f, cur - v, v);
    float id = cur - 0.2f * cur;
    float s = (vd > 1.0f) ? 1.0f : 0.f;
    v = (1.0f - s) * vd;
    cur = id + inp;
    cnt += s;
  }
  out[idx] = cnt;
}

extern "C" void kernel_launch(void* const* d_in, const int* in_sizes, int n_in,
                              void* d_out, int out_size, void* d_ws,
                              size_t ws_size, hipStream_t stream) {
  const float* x    = (const float*)d_in[0];  // (256,32,2312)
  const float* W1   = (const float*)d_in[1];  // (1024,2312)
  const float* b1   = (const float*)d_in[2];
  const float* W2   = (const float*)d_in[3];  // (1024,1024)
  const float* b2   = (const float*)d_in[4];
  const float* Wout = (const float*)d_in[5];  // (10,1024)
  const float* bout = (const float*)d_in[6];

  // Fragment-plane sizes (elements): W1 64 n16 x 74 k32 x 512 = 2,424,832;
  // W2 64 x 32 x 512 = 1,048,576.
  const long PL1 = 64L * NK1 * 512;
  const long PL2 = 64L * NK2 * 512;

  // ws layout (bytes):
  //   [0, 16.78M)      : W1p (2 planes, 9.70M) + W2p (2 planes, 4.19M) --
  //                      dead after GEMM2; S2 (fp16, 16.78M) ALIASES this
  //                      region (stream-sequential safe; rebuilt each call).
  //   [16.78M, 50.33M) : bufI (fp32, 33.55M)
  //   [50.33M, 67.11M) : S1 (fp16, 16.78M)
  //   [67.11M, 67.44M) : buf3 (fp32, 0.33M)
  char* base = (char*)d_ws;
  const long S2_BYTES = (long)TM * TH * 2;  // 16,777,216
  f16_t* W1p  = (f16_t*)base;
  f16_t* W2p  = (f16_t*)(base + 2 * PL1 * 2);  // after 9,699,328 B
  float* bufI = (float*)(base + S2_BYTES);
  f16_t* S1   = (f16_t*)(base + S2_BYTES + (long)TM * TH * 4);
  float* buf3 = (float*)(base + S2_BYTES + (long)TM * TH * 4 + (long)TM * TH * 2);
  f16_t* S2   = (f16_t*)base;

  split_w_frag<<<64 * NK1 / 4, 256, 0, stream>>>(W1, W1p, PL1, TIN, NK1);
  split_w_frag<<<64 * NK2 / 4, 256, 0, stream>>>(W2, W2p, PL2, TH, NK2);

  // GEMM1: row r=(t,b): x offset = t*2312 + b*(32*2312)
  snn_gemm1<<<512, 256, 0, stream>>>(x, (long)TIN, (long)TT * TIN, W1p, PL1,
                                     NK1, TIN, b1, bufI, TH);

  lif_scan_f16<<<(TB * TH) / 256, 256, 0, stream>>>(bufI, S1);

  // GEMM2: S1 row-major [8192][1024]: sT=256*1024, sB=1024
  snn_gemm2<<<512, 256, 0, stream>>>(S1, (long)TB * TH, (long)TH, W2p, PL2,
                                     NK2, b2, bufI, TH);

  lif_scan_f16<<<(TB * TH) / 256, 256, 0, stream>>>(bufI, S2);

  gemm3_kernel<<<(TM * 64) / 256, 256, 0, stream>>>(S2, Wout, bout, buf3);

  scan_out<<<(TB * TOUT + 255) / 256, 256, 0, stream>>>(buf3, (float*)d_out);
}

// Round 6
// 329.052 us; speedup vs baseline: 1.0899x; 1.0899x over previous
//
#include <hip/hip_runtime.h>

// SNN: 3-layer LIF, B=256, T=32, H=1024, IN=2312, OUT=10.
// Round-5 (153us G1): fp16 2-plane 3-pass, LDS-staged, 2 barriers/tile.
// Round-6 FAILED: 1 block/CU -> barrier-serialized.
// Round-7 FAILED: FETCH 320MB. Round-8 (same FETCH): root cause finally
//   isolated = block->tile MAPPING, not B's staging path. nblk-fast made
//   co-resident blocks span all 8 B slices (9.7MB vs 4MB XCD L2 -> thrash).
// Round-9: mblk-FAST mapping (grid dim3(64,8)): 64 consecutive blocks share
//   one nblk -> B slice 2.42MB stays L2-hot (round-5 measured 100MB FETCH
//   with this order). Keeps round-8's verified structure: B via
//   global_load_lds from fragment-ordered planes (conflict-free), A
//   reg-staged+split to fragment-order LDS, full double-buffer, ONE
//   barrier/K-tile. BM=BN=128, 4 waves 2Mx2N (64x64/wave), grid 512 =
//   2 blocks/CU, LDS 64KB. Per-CU floors: MFMA 138k cyc, LDS 142k cyc.

#define TB 256
#define TT 32
#define TH 1024
#define TIN 2312
#define TOUT 10
#define TM (TT * TB)   // 8192 rows = (t,b)
#define NK1 74         // K-tiles of 32 for GEMM1 (2368 = 74*32)
#define NK2 32         // K-tiles for GEMM2 (1024)
#define FR 512         // f16 elems per (16 x 32) fragment

typedef _Float16 f16_t;
typedef f16_t f16x8 __attribute__((ext_vector_type(8)));
typedef float floatx4 __attribute__((ext_vector_type(4)));

__device__ __forceinline__ void split2h(float v, f16_t& a, f16_t& b) {
  a = (f16_t)v;
  b = (f16_t)(v - (float)a);
}

// async 16B global->LDS; LDS dest = wave-uniform base + lane*16.
__device__ __forceinline__ void gload16(const void* g, void* l) {
  __builtin_amdgcn_global_load_lds(
      (const __attribute__((address_space(1))) void*)g,
      (__attribute__((address_space(3))) void*)l, 16, 0, 0);
}

// W (N x K) -> 2 fp16 planes in MFMA-B-fragment order:
// P[q*plane + fid*512 + lane*8 + e] =
//   split_q(W[(n16*16 + (lane&15))*K + k32*32 + (lane>>4)*8 + e]),
// fid = n16*nk32 + k32, zero for k >= K. (Verified absmax 0.0, rounds 7-8.)
__global__ __launch_bounds__(256) void split_w_frag(
    const float* __restrict__ W, f16_t* __restrict__ P, long plane,
    int K, int nk32) {
  const int fid = blockIdx.x * 4 + (threadIdx.x >> 6);
  const int lane = threadIdx.x & 63;
  const int n16 = fid / nk32, k32 = fid - n16 * nk32;
  const long row = n16 * 16 + (lane & 15);
  const int k0 = k32 * 32 + (lane >> 4) * 8;
  float t[8];
  if (k0 + 8 <= K) {
    float4 v0 = *(const float4*)(W + row * K + k0);
    float4 v1 = *(const float4*)(W + row * K + k0 + 4);
    t[0] = v0.x; t[1] = v0.y; t[2] = v0.z; t[3] = v0.w;
    t[4] = v1.x; t[5] = v1.y; t[6] = v1.z; t[7] = v1.w;
  } else {
    #pragma unroll
    for (int e = 0; e < 8; ++e) t[e] = 0.f;
  }
  f16x8 h0, h1;
  #pragma unroll
  for (int e = 0; e < 8; ++e) {
    f16_t a, b;
    split2h(t[e], a, b);
    h0[e] = a; h1[e] = b;
  }
  const long o = (long)fid * 512 + lane * 8;
  *(f16x8*)(P + o) = h0;
  *(f16x8*)(P + plane + o) = h1;
}

// GEMM1: 3 fp16 passes (a0b0, a1b0, a0b1); A = x fp32 split in-kernel,
// B = W1 fragment planes via global_load_lds. One barrier per K-tile.
// Grid dim3(64, 8): mblk = blockIdx.x (FAST -> B slice L2-resident),
// nblk = blockIdx.y.
__global__ __launch_bounds__(256, 2) void snn_gemm1(
    const float* __restrict__ Af, long sT, long sB,
    const f16_t* __restrict__ Bf, long planeB, int nk32, int K,
    const float* __restrict__ bias, float* __restrict__ C, int N) {
  __shared__ f16_t As[2 * 2 * 8 * FR];  // [buf][plane][m16][512]  32 KB
  __shared__ f16_t Bs[2 * 2 * 8 * FR];  // [buf][plane][n16][512]  32 KB

  const int tid = threadIdx.x;
  const int wave = tid >> 6, lane = tid & 63;
  const int quad = lane >> 4, l16 = lane & 15;
  const int wm = (wave & 1) * 64, wn = (wave >> 1) * 64;
  const int a16 = (wave & 1) * 4, b16 = (wave >> 1) * 4;  // frag bases
  const int mblk = blockIdx.x, nblk = blockIdx.y;
  const long m0 = (long)mblk * 128, n0 = (long)nblk * 128;

  floatx4 acc[4][4];
  #pragma unroll
  for (int i = 0; i < 4; ++i)
    #pragma unroll
    for (int j = 0; j < 4; ++j) acc[i][j] = (floatx4){0.f, 0.f, 0.f, 0.f};

  // A staging: thread owns (row cr, k-half ch): 16 fp32 -> 2x2 f16x8 frags
  const int cr = tid >> 1, ch = tid & 1;
  const int am16 = cr >> 4;
  const int lnA0 = (cr & 15) | ((2 * ch) << 4);
  const int lnA1 = (cr & 15) | ((2 * ch + 1) << 4);
  float4 xv[4];
  const float* xrow = Af + ((m0 + cr) >> 8) * sT + ((m0 + cr) & 255) * sB;

  auto prefetchA = [&](int kt) {
    const int k0 = kt * 32 + ch * 16;
    #pragma unroll
    for (int u = 0; u < 4; ++u)
      xv[u] = (k0 + u * 4 < K) ? *(const float4*)(xrow + k0 + u * 4)
                               : float4{0.f, 0.f, 0.f, 0.f};
  };

  auto commitA = [&](int buf) {
    #pragma unroll
    for (int half = 0; half < 2; ++half) {
      const float* p = (const float*)&xv[half * 2];
      f16x8 p0, p1;
      #pragma unroll
      for (int e = 0; e < 8; ++e) {
        f16_t a, b;
        split2h(p[e], a, b);
        p0[e] = a; p1[e] = b;
      }
      const int ln = half ? lnA1 : lnA0;
      *(f16x8*)(&As[((buf * 2 + 0) * 8 + am16) * FR + ln * 8]) = p0;
      *(f16x8*)(&As[((buf * 2 + 1) * 8 + am16) * FR + ln * 8]) = p1;
    }
  };

  // B staging: 16 chunks of 1KB (2 planes x 8 n16-frags); wave w does 4.
  const long nbase = (n0 >> 4) * (long)nk32;
  auto gloadB = [&](int kt, int buf) {
    #pragma unroll
    for (int c = 0; c < 4; ++c) {
      const int chk = wave * 4 + c;
      const int pl = chk >> 3, n16 = chk & 7;
      const f16_t* src = Bf + pl * planeB +
                         (nbase + (long)n16 * nk32 + kt) * FR + lane * 8;
      gload16(src, &Bs[((buf * 2 + pl) * 8 + n16) * FR]);
    }
  };

  // prologue: tile0 staged; xv <- A(1)
  prefetchA(0);
  gloadB(0, 0);
  commitA(0);
  prefetchA(1);
  __syncthreads();  // drains gloadB(0) + commit(0) visible

  for (int kt = 0; kt < nk32; ++kt) {
    const int cur = kt & 1;
    // invariant: As/Bs[cur] ready; xv = A(kt+1)
    if (kt + 1 < nk32) {
      gloadB(kt + 1, cur ^ 1);  // in flight across this MFMA phase
      commitA(cur ^ 1);         // xv already arrived (prev barrier drained)
    }
    if (kt + 2 < nk32) prefetchA(kt + 2);

    f16x8 afr[2][4];
    #pragma unroll
    for (int pl = 0; pl < 2; ++pl)
      #pragma unroll
      for (int i = 0; i < 4; ++i)
        afr[pl][i] = *(const f16x8*)(
            &As[((cur * 2 + pl) * 8 + a16 + i) * FR + lane * 8]);

    #pragma unroll
    for (int pb = 0; pb < 2; ++pb) {
      f16x8 bfr[4];
      #pragma unroll
      for (int j = 0; j < 4; ++j)
        bfr[j] = *(const f16x8*)(
            &Bs[((cur * 2 + pb) * 8 + b16 + j) * FR + lane * 8]);
      const int pamax = 1 - pb;  // passes (0,0),(1,0),(0,1)
      #pragma unroll
      for (int pa = 0; pa < 2; ++pa) {
        if (pa > pamax) break;
        #pragma unroll
        for (int i = 0; i < 4; ++i)
          #pragma unroll
          for (int j = 0; j < 4; ++j)
            acc[i][j] = __builtin_amdgcn_mfma_f32_16x16x32_f16(
                afr[pa][i], bfr[j], acc[i][j], 0, 0, 0);
      }
    }
    __syncthreads();  // frag reads done; gloadB(kt+1)/commit drained+visible
  }

  // epilogue: C/D layout col=lane&15, row=quad*4+reg (verified)
  #pragma unroll
  for (int j = 0; j < 4; ++j) {
    const long col = n0 + wn + j * 16 + l16;
    const float bvv = bias[col];
    #pragma unroll
    for (int i = 0; i < 4; ++i) {
      const long row0 = m0 + wm + i * 16 + quad * 4;
      #pragma unroll
      for (int g = 0; g < 4; ++g)
        C[(row0 + g) * (long)N + col] = acc[i][j][g] + bvv;
    }
  }
}

// GEMM2: A = spikes (fp16 exact, 1 plane, reg-staged copy), B = W2
// fragment planes via global_load_lds, 2 passes. Same one-barrier loop.
__global__ __launch_bounds__(256, 2) void snn_gemm2(
    const f16_t* __restrict__ Ab, long sT, long sB,
    const f16_t* __restrict__ Bf, long planeB, int nk32,
    const float* __restrict__ bias, float* __restrict__ C, int N) {
  __shared__ f16_t As[2 * 8 * FR];      // [buf][m16][512]  16 KB
  __shared__ f16_t Bs[2 * 2 * 8 * FR];  // 32 KB

  const int tid = threadIdx.x;
  const int wave = tid >> 6, lane = tid & 63;
  const int quad = lane >> 4, l16 = lane & 15;
  const int wm = (wave & 1) * 64, wn = (wave >> 1) * 64;
  const int a16 = (wave & 1) * 4, b16 = (wave >> 1) * 4;
  const int mblk = blockIdx.x, nblk = blockIdx.y;
  const long m0 = (long)mblk * 128, n0 = (long)nblk * 128;

  floatx4 acc[4][4];
  #pragma unroll
  for (int i = 0; i < 4; ++i)
    #pragma unroll
    for (int j = 0; j < 4; ++j) acc[i][j] = (floatx4){0.f, 0.f, 0.f, 0.f};

  const int cr = tid >> 1, ch = tid & 1;
  const int am16 = cr >> 4;
  const int lnA0 = (cr & 15) | ((2 * ch) << 4);
  const int lnA1 = (cr & 15) | ((2 * ch + 1) << 4);
  f16x8 av[2];
  const f16_t* arow = Ab + ((m0 + cr) >> 8) * sT + ((m0 + cr) & 255) * sB;

  auto prefetchA = [&](int kt) {
    const f16_t* p = arow + kt * 32 + ch * 16;
    av[0] = *(const f16x8*)p;
    av[1] = *(const f16x8*)(p + 8);
  };

  auto commitA = [&](int buf) {
    *(f16x8*)(&As[(buf * 8 + am16) * FR + lnA0 * 8]) = av[0];
    *(f16x8*)(&As[(buf * 8 + am16) * FR + lnA1 * 8]) = av[1];
  };

  const long nbase = (n0 >> 4) * (long)nk32;
  auto gloadB = [&](int kt, int buf) {
    #pragma unroll
    for (int c = 0; c < 4; ++c) {
      const int chk = wave * 4 + c;
      const int pl = chk >> 3, n16 = chk & 7;
      const f16_t* src = Bf + pl * planeB +
                         (nbase + (long)n16 * nk32 + kt) * FR + lane * 8;
      gload16(src, &Bs[((buf * 2 + pl) * 8 + n16) * FR]);
    }
  };

  prefetchA(0);
  gloadB(0, 0);
  commitA(0);
  prefetchA(1);
  __syncthreads();

  for (int kt = 0; kt < nk32; ++kt) {
    const int cur = kt & 1;
    if (kt + 1 < nk32) {
      gloadB(kt + 1, cur ^ 1);
      commitA(cur ^ 1);
    }
    if (kt + 2 < nk32) prefetchA(kt + 2);

    f16x8 afr[4];
    #pragma unroll
    for (int i = 0; i < 4; ++i)
      afr[i] = *(const f16x8*)(&As[(cur * 8 + a16 + i) * FR + lane * 8]);

    #pragma unroll
    for (int pb = 0; pb < 2; ++pb) {
      f16x8 bfr[4];
      #pragma unroll
      for (int j = 0; j < 4; ++j)
        bfr[j] = *(const f16x8*)(
            &Bs[((cur * 2 + pb) * 8 + b16 + j) * FR + lane * 8]);
      #pragma unroll
      for (int i = 0; i < 4; ++i)
        #pragma unroll
        for (int j = 0; j < 4; ++j)
          acc[i][j] = __builtin_amdgcn_mfma_f32_16x16x32_f16(
              afr[i], bfr[j], acc[i][j], 0, 0, 0);
    }
    __syncthreads();
  }

  #pragma unroll
  for (int j = 0; j < 4; ++j) {
    const long col = n0 + wn + j * 16 + l16;
    const float bvv = bias[col];
    #pragma unroll
    for (int i = 0; i < 4; ++i) {
      const long row0 = m0 + wm + i * 16 + quad * 4;
      #pragma unroll
      for (int g = 0; g < 4; ++g)
        C[(row0 + g) * (long)N + col] = acc[i][j][g] + bvv;
    }
  }
}

// LIF scan, fp32 in -> fp16 spikes out (spikes {0,1} exact in fp16).
__global__ __launch_bounds__(256) void lif_scan_f16(const float* __restrict__ I,
                                                    f16_t* __restrict__ S) {
  int idx = blockIdx.x * 256 + threadIdx.x;
  float v = 0.f, cur = 0.f;
  #pragma unroll
  for (int t = 0; t < TT; ++t) {
    float inp = I[(long)t * (TB * TH) + idx];
    float vd = fmaf(0.05f, cur - v, v);
    float id = cur - 0.2f * cur;
    float s = (vd > 1.0f) ? 1.0f : 0.f;
    v = (1.0f - s) * vd;
    cur = id + inp;
    S[(long)t * (TB * TH) + idx] = (f16_t)s;
  }
}

// GEMM3: one wave per row; I3[r][o] = S2[r][:] . Wout[o][:] + bout[o]
__global__ __launch_bounds__(256) void gemm3_kernel(
    const f16_t* __restrict__ S2, const float* __restrict__ Wout,
    const float* __restrict__ bout, float* __restrict__ I3) {
  int wv = (blockIdx.x * blockDim.x + threadIdx.x) >> 6;
  int lane = threadIdx.x & 63;
  if (wv >= TM) return;
  const f16_t* srow = S2 + (long)wv * TH;
  float acc[TOUT];
  #pragma unroll
  for (int o = 0; o < TOUT; ++o) acc[o] = 0.f;
  for (int k = lane; k < TH; k += 64) {
    float s = (float)srow[k];
    #pragma unroll
    for (int o = 0; o < TOUT; ++o) acc[o] = fmaf(s, Wout[o * TH + k], acc[o]);
  }
  #pragma unroll
  for (int off = 32; off > 0; off >>= 1)
    #pragma unroll
    for (int o = 0; o < TOUT; ++o) acc[o] += __shfl_down(acc[o], off, 64);
  if (lane == 0) {
    #pragma unroll
    for (int o = 0; o < TOUT; ++o) I3[(long)wv * TOUT + o] = acc[o] + bout[o];
  }
}

__global__ __launch_bounds__(256) void scan_out(const float* __restrict__ I3,
                                                float* __restrict__ out) {
  int idx = blockIdx.x * blockDim.x + threadIdx.x;
  if (idx >= TB * TOUT) return;
  float v = 0.f, cur = 0.f, cnt = 0.f;
  #pragma unroll
  for (int t = 0; t < TT; ++t) {
    float inp = I3[(long)t * (TB * TOUT) + idx];
    float vd = fmaf(0.05f, cur - v, v);
    float id = cur - 0.2f * cur;
    float s = (vd > 1.0f) ? 1.0f : 0.f;
    v = (1.0f - s) * vd;
    cur = id + inp;
    cnt += s;
  }
  out[idx] = cnt;
}

extern "C" void kernel_launch(void* const* d_in, const int* in_sizes, int n_in,
                              void* d_out, int out_size, void* d_ws,
                              size_t ws_size, hipStream_t stream) {
  const float* x    = (const float*)d_in[0];  // (256,32,2312)
  const float* W1   = (const float*)d_in[1];  // (1024,2312)
  const float* b1   = (const float*)d_in[2];
  const float* W2   = (const float*)d_in[3];  // (1024,1024)
  const float* b2   = (const float*)d_in[4];
  const float* Wout = (const float*)d_in[5];  // (10,1024)
  const float* bout = (const float*)d_in[6];

  // Fragment-plane sizes (elements): W1 64 n16 x 74 k32 x 512 = 2,424,832;
  // W2 64 x 32 x 512 = 1,048,576.
  const long PL1 = 64L * NK1 * 512;
  const long PL2 = 64L * NK2 * 512;

  // ws layout (bytes):
  //   [0, 16.78M)      : W1p (2 planes, 9.70M) + W2p (2 planes, 4.19M) --
  //                      dead after GEMM2; S2 (fp16, 16.78M) ALIASES this
  //                      region (stream-sequential safe; rebuilt each call).
  //   [16.78M, 50.33M) : bufI (fp32, 33.55M)
  //   [50.33M, 67.11M) : S1 (fp16, 16.78M)
  //   [67.11M, 67.44M) : buf3 (fp32, 0.33M)
  char* base = (char*)d_ws;
  const long S2_BYTES = (long)TM * TH * 2;  // 16,777,216
  f16_t* W1p  = (f16_t*)base;
  f16_t* W2p  = (f16_t*)(base + 2 * PL1 * 2);  // after 9,699,328 B
  float* bufI = (float*)(base + S2_BYTES);
  f16_t* S1   = (f16_t*)(base + S2_BYTES + (long)TM * TH * 4);
  float* buf3 = (float*)(base + S2_BYTES + (long)TM * TH * 4 + (long)TM * TH * 2);
  f16_t* S2   = (f16_t*)base;

  split_w_frag<<<64 * NK1 / 4, 256, 0, stream>>>(W1, W1p, PL1, TIN, NK1);
  split_w_frag<<<64 * NK2 / 4, 256, 0, stream>>>(W2, W2p, PL2, TH, NK2);

  // GEMM1: row r=(t,b): x offset = t*2312 + b*(32*2312)
  snn_gemm1<<<dim3(64, 8), 256, 0, stream>>>(
      x, (long)TIN, (long)TT * TIN, W1p, PL1, NK1, TIN, b1, bufI, TH);

  lif_scan_f16<<<(TB * TH) / 256, 256, 0, stream>>>(bufI, S1);

  // GEMM2: S1 row-major [8192][1024]: sT=256*1024, sB=1024
  snn_gemm2<<<dim3(64, 8), 256, 0, stream>>>(
      S1, (long)TB * TH, (long)TH, W2p, PL2, NK2, b2, bufI, TH);

  lif_scan_f16<<<(TB * TH) / 256, 256, 0, stream>>>(bufI, S2);

  gemm3_kernel<<<(TM * 64) / 256, 256, 0, stream>>>(S2, Wout, bout, buf3);

  scan_out<<<(TB * TOUT + 255) / 256, 256, 0, stream>>>(buf3, (float*)d_out);
}